// Round 8
// baseline (93.517 us; speedup 1.0000x reference)
//
#include <hip/hip_runtime.h>
#include <math.h>

#define DM 256
#define DI 512
#define BB 4
#define LL 2048
#define NC 64
#define CH (LL / NC)  // 32

typedef short bf16x8 __attribute__((ext_vector_type(8)));
typedef float f32x4 __attribute__((ext_vector_type(4)));
typedef unsigned short u16;

__device__ inline u16 f2bf(float f) {
    union { float f; unsigned u; } v;
    v.f = f;
    return (u16)((v.u + 0x7FFF + ((v.u >> 16) & 1)) >> 16);
}
__device__ inline float bf2f(u16 h) {
    union { unsigned u; float f; } v;
    v.u = ((unsigned)h) << 16;
    return v.f;
}

// ---------------------------------------------------------------------------
// K0: ALL prep in one launch.
// bid [0,512):   x[b][m][l] fp32 -> xt[b][l][m] bf16 (64x64 transpose tiles)
// bid [512,768): W_in cvt   bid [768,896): W_out cvt   bid [896,920): W_x cvt
// ---------------------------------------------------------------------------
__global__ __launch_bounds__(256) void k_prep(const float* __restrict__ x,
                                              const float* __restrict__ W_in,
                                              const float* __restrict__ W_out,
                                              const float* __restrict__ W_x,
                                              u16* __restrict__ xt,
                                              u16* __restrict__ wbf_in,
                                              u16* __restrict__ wbf_out,
                                              u16* __restrict__ wbf_x) {
    const int bid = blockIdx.x;
    const int t = threadIdx.x;
    if (bid < 512) {
        __shared__ float tile[64][65];
        const int lb = bid & 31, mb = (bid >> 5) & 3, b = bid >> 7;
        const int m0 = mb * 64, l0 = lb * 64;
        const float* xb = x + ((size_t)b * DM + m0) * LL + l0;
#pragma unroll
        for (int i = 0; i < 16; i++) {
            int idx = t + i * 256;
            int r = idx >> 6, c = idx & 63;
            tile[r][c] = xb[(size_t)r * LL + c];
        }
        __syncthreads();
        u16* ob = xt + ((size_t)b * LL + l0) * DM + m0;
#pragma unroll
        for (int i = 0; i < 16; i++) {
            int idx = t + i * 256;
            int r = idx >> 6, c = idx & 63;
            ob[(size_t)r * DM + c] = f2bf(tile[c][r]);
        }
        return;
    }
    const float* src;
    u16* dst;
    int i4;
    if (bid < 768) { src = W_in; dst = wbf_in; i4 = (bid - 512) * 256 + t; }
    else if (bid < 896) { src = W_out; dst = wbf_out; i4 = (bid - 768) * 256 + t; }
    else { src = W_x; dst = wbf_x; i4 = (bid - 896) * 256 + t; }
    float4 v = ((const float4*)src)[i4];
    unsigned o0 = (unsigned)f2bf(v.x) | ((unsigned)f2bf(v.y) << 16);
    unsigned o1 = (unsigned)f2bf(v.z) | ((unsigned)f2bf(v.w) << 16);
    ((uint2*)dst)[i4] = make_uint2(o0, o1);
}

// ---------------------------------------------------------------------------
// K1: MFMA GEMM  xz[b][l][c] (bf16) = sum_m xt[b][l][m] * W_in[c][m]
// 128x128 tile, BK=64, 4 waves 2x2, 16x16x32 bf16 MFMA, XOR swizzle.
// ---------------------------------------------------------------------------
__global__ __launch_bounds__(256) void k_gemm_in(const u16* __restrict__ xt,
                                                 const u16* __restrict__ Wb,
                                                 u16* __restrict__ xz) {
    __shared__ short As[128 * 64];
    __shared__ short Bs[128 * 64];
    const int b = blockIdx.z;
    const int l0 = blockIdx.x * 128;
    const int c0 = blockIdx.y * 128;
    const int t = threadIdx.x;
    const int lane = t & 63, wv = t >> 6;
    const int wr = wv >> 1, wc = wv & 1;
    const u16* xb = xt + (size_t)b * LL * DM;
    f32x4 acc[4][4] = {};
    for (int k0 = 0; k0 < DM; k0 += 64) {
#pragma unroll
        for (int i = 0; i < 4; i++) {
            int ci = t + i * 256;
            int r = ci >> 3;
            int cb = (ci & 7) * 16;
            int pd = r * 128 + (cb ^ ((r & 7) << 4));
            *(float4*)((char*)As + pd) =
                *(const float4*)((const char*)(xb + (size_t)(l0 + r) * DM + k0) + cb);
            *(float4*)((char*)Bs + pd) =
                *(const float4*)((const char*)(Wb + (size_t)(c0 + r) * DM + k0) + cb);
        }
        __syncthreads();
#pragma unroll
        for (int kk = 0; kk < 2; kk++) {
            const int lcb = kk * 64 + (lane >> 4) * 16;
            bf16x8 af[4], bfr[4];
#pragma unroll
            for (int mi = 0; mi < 4; mi++) {
                int r = wr * 64 + mi * 16 + (lane & 15);
                af[mi] = *(const bf16x8*)((const char*)As + r * 128 + (lcb ^ ((r & 7) << 4)));
            }
#pragma unroll
            for (int ni = 0; ni < 4; ni++) {
                int r = wc * 64 + ni * 16 + (lane & 15);
                bfr[ni] = *(const bf16x8*)((const char*)Bs + r * 128 + (lcb ^ ((r & 7) << 4)));
            }
#pragma unroll
            for (int mi = 0; mi < 4; mi++)
#pragma unroll
                for (int ni = 0; ni < 4; ni++)
                    acc[mi][ni] = __builtin_amdgcn_mfma_f32_16x16x32_bf16(
                        af[mi], bfr[ni], acc[mi][ni], 0, 0, 0);
        }
        __syncthreads();
    }
    u16* ob = xz + (size_t)b * LL * 1024;
#pragma unroll
    for (int mi = 0; mi < 4; mi++) {
#pragma unroll
        for (int q = 0; q < 4; q++) {
            int l = l0 + wr * 64 + mi * 16 + (lane >> 4) * 4 + q;
#pragma unroll
            for (int ni = 0; ni < 4; ni++) {
                int c = c0 + wc * 64 + ni * 16 + (lane & 15);
                ob[(size_t)l * 1024 + c] = f2bf(acc[mi][ni][q]);
            }
        }
    }
}

// ---------------------------------------------------------------------------
// K2a: depthwise conv k=3 + bias + silu, bf16->bf16, 8 d's/thread, 2048 blocks
// ---------------------------------------------------------------------------
__global__ __launch_bounds__(256) void k_conv(const u16* __restrict__ xz,
                                              const float* __restrict__ Wdw,
                                              const float* __restrict__ bdw,
                                              u16* __restrict__ u_bf) {
    int idx = blockIdx.x * 256 + threadIdx.x;  // over BB*LL*64 groups of 8
    int g = idx & 63;
    int l = (idx >> 6) & (LL - 1);
    int b = idx >> 17;
    int d0 = g * 8;
    const u16* row = xz + ((size_t)b * LL + l) * 1024 + d0;
    ushort4 c0a = *(const ushort4*)(row);
    ushort4 c0b = *(const ushort4*)(row + 4);
    ushort4 cma, cmb, cpa, cpb;
    if (l > 0) { cma = *(const ushort4*)(row - 1024); cmb = *(const ushort4*)(row - 1020); }
    else { cma = make_ushort4(0, 0, 0, 0); cmb = cma; }
    if (l < LL - 1) { cpa = *(const ushort4*)(row + 1024); cpb = *(const ushort4*)(row + 1028); }
    else { cpa = make_ushort4(0, 0, 0, 0); cpb = cpa; }
    u16 xm[8] = {cma.x, cma.y, cma.z, cma.w, cmb.x, cmb.y, cmb.z, cmb.w};
    u16 x0[8] = {c0a.x, c0a.y, c0a.z, c0a.w, c0b.x, c0b.y, c0b.z, c0b.w};
    u16 xp[8] = {cpa.x, cpa.y, cpa.z, cpa.w, cpb.x, cpb.y, cpb.z, cpb.w};
    u16 out[8];
#pragma unroll
    for (int j = 0; j < 8; j++) {
        int d = d0 + j;
        float v = bdw[d] + Wdw[d * 3] * bf2f(xm[j]) + Wdw[d * 3 + 1] * bf2f(x0[j]) +
                  Wdw[d * 3 + 2] * bf2f(xp[j]);
        float uu = v / (1.f + __expf(-v));
        out[j] = f2bf(uu);
    }
    u16* ou = u_bf + ((size_t)b * LL + l) * DI + d0;
    *(ushort4*)(ou) = make_ushort4(out[0], out[1], out[2], out[3]);
    *(ushort4*)(ou + 4) = make_ushort4(out[4], out[5], out[6], out[7]);
}

// ---------------------------------------------------------------------------
// K2b: split-K MFMA GEMM  xdbl_p[kp][bl][c] = sum_{d in kp-chunk} u*Wx
// grid = 512 blocks: (bl-tile of 64 rows) x (kp in 0..3, K=128 each)
// ---------------------------------------------------------------------------
__global__ __launch_bounds__(256) void k_xdbl(const u16* __restrict__ u_bf,
                                              const u16* __restrict__ Wxb,
                                              float* __restrict__ xdbl_p) {
    __shared__ short Us[64 * 64];
    __shared__ short Ws[48 * 64];
    const int bl0 = (blockIdx.x >> 2) * 64;
    const int kp = blockIdx.x & 3;
    const int t = threadIdx.x;
    const int lane = t & 63, wv = t >> 6;
    f32x4 acc[3] = {};
#pragma unroll
    for (int ks = 0; ks < 2; ks++) {
        const int k0 = kp * 128 + ks * 64;
        if (ks) __syncthreads();
#pragma unroll
        for (int i = 0; i < 2; i++) {
            int ci = t + i * 256;
            int r = ci >> 3;
            int cb = (ci & 7) * 16;
            int pd = r * 128 + (cb ^ ((r & 7) << 4));
            *(float4*)((char*)Us + pd) =
                *(const float4*)((const char*)(u_bf + (size_t)(bl0 + r) * DI + k0) + cb);
            if (ci < 384)
                *(float4*)((char*)Ws + pd) =
                    *(const float4*)((const char*)(Wxb + (size_t)r * DI + k0) + cb);
        }
        __syncthreads();
#pragma unroll
        for (int kk = 0; kk < 2; kk++) {
            int lcb = kk * 64 + (lane >> 4) * 16;
            int ra = wv * 16 + (lane & 15);
            bf16x8 af = *(const bf16x8*)((const char*)Us + ra * 128 + (lcb ^ ((ra & 7) << 4)));
#pragma unroll
            for (int ni = 0; ni < 3; ni++) {
                int r2 = ni * 16 + (lane & 15);
                bf16x8 bfr = *(const bf16x8*)((const char*)Ws + r2 * 128 + (lcb ^ ((r2 & 7) << 4)));
                acc[ni] = __builtin_amdgcn_mfma_f32_16x16x32_bf16(af, bfr, acc[ni], 0, 0, 0);
            }
        }
    }
#pragma unroll
    for (int ni = 0; ni < 3; ni++)
#pragma unroll
        for (int q = 0; q < 4; q++) {
            int l = bl0 + wv * 16 + (lane >> 4) * 4 + q;
            int c = ni * 16 + (lane & 15);
            xdbl_p[((size_t)kp * BB * LL + l) * 48 + c] = acc[ni][q];
        }
}

// ---------------------------------------------------------------------------
// K3: reduce split-K partials -> xdbl (final) ; delta = softplus(...) -> bf16
// ---------------------------------------------------------------------------
__global__ __launch_bounds__(256) void k_delta(const float* __restrict__ xdbl_p,
                                               const float* __restrict__ Wdt,
                                               const float* __restrict__ bdt,
                                               float* __restrict__ xdbl,
                                               u16* __restrict__ delta_bf) {
    __shared__ float xd[16][52];
    const int bl0 = blockIdx.x * 16;
    const int t = threadIdx.x;
#pragma unroll
    for (int i = 0; i < 3; i++) {
        int idx = t + i * 256;  // 0..767 = 16 rows x 48 cols
        int l = idx / 48, c = idx - l * 48;
        size_t off = (size_t)(bl0 + l) * 48 + c;
        float s = xdbl_p[off] + xdbl_p[(size_t)BB * LL * 48 + off] +
                  xdbl_p[(size_t)2 * BB * LL * 48 + off] +
                  xdbl_p[(size_t)3 * BB * LL * 48 + off];
        xd[l][c] = s;
        xdbl[off] = s;
    }
    __syncthreads();
    float wr0[16], wr1[16];
    {
        const float4* wp0 = (const float4*)(Wdt + (size_t)t * 16);
        const float4* wp1 = (const float4*)(Wdt + (size_t)(t + 256) * 16);
#pragma unroll
        for (int q = 0; q < 4; q++) {
            float4 w = wp0[q];
            wr0[q * 4] = w.x; wr0[q * 4 + 1] = w.y; wr0[q * 4 + 2] = w.z; wr0[q * 4 + 3] = w.w;
            float4 u = wp1[q];
            wr1[q * 4] = u.x; wr1[q * 4 + 1] = u.y; wr1[q * 4 + 2] = u.z; wr1[q * 4 + 3] = u.w;
        }
    }
    const float b0 = bdt[t], b1 = bdt[t + 256];
#pragma unroll 4
    for (int ll = 0; ll < 16; ll++) {
        float a0 = b0, a1 = b1;
#pragma unroll
        for (int q = 0; q < 4; q++) {
            f32x4 xv = *(const f32x4*)&xd[ll][q * 4];
#pragma unroll
            for (int j = 0; j < 4; j++) {
                a0 += wr0[q * 4 + j] * xv[j];
                a1 += wr1[q * 4 + j] * xv[j];
            }
        }
        float sp0 = fmaxf(a0, 0.f) + __logf(1.f + __expf(-fabsf(a0)));
        float sp1 = fmaxf(a1, 0.f) + __logf(1.f + __expf(-fabsf(a1)));
        delta_bf[(size_t)(bl0 + ll) * DI + t] = f2bf(sp0);
        delta_bf[(size_t)(bl0 + ll) * DI + t + 256] = f2bf(sp1);
    }
}

// ---------------------------------------------------------------------------
// K4a: per-chunk local scan. B/C rows read DIRECTLY from global with
// block-uniform addresses -> compiler scalar (s_load) path, no LDS staging.
// ---------------------------------------------------------------------------
__global__ __launch_bounds__(256) void k_scanA(const u16* __restrict__ delta_bf,
                                               const float* __restrict__ xdbl,
                                               const u16* __restrict__ u_bf,
                                               const float* __restrict__ A_log,
                                               u16* __restrict__ hend,
                                               float* __restrict__ dsum) {
    const int t = threadIdx.x;
    const int d = blockIdx.y * 256 + t;
    const int b = blockIdx.z;
    const int c = blockIdx.x;
    const int l0 = c * CH;
    const size_t bl0 = (size_t)b * LL + l0;
    float Av[16];
    bool fast = true;
    {
        const float4* Ar = (const float4*)(A_log + (size_t)d * 16);
#pragma unroll
        for (int q = 0; q < 4; q++) {
            float4 a = Ar[q];
            Av[q * 4] = -__expf(a.x); Av[q * 4 + 1] = -__expf(a.y);
            Av[q * 4 + 2] = -__expf(a.z); Av[q * 4 + 3] = -__expf(a.w);
        }
#pragma unroll
        for (int n = 0; n < 16; n++)
            fast = fast && (fabsf(Av[n] + (float)(n + 1)) < 1e-4f * (n + 1));
    }
    const u16* dl = delta_bf + bl0 * DI + d;
    const u16* ul = u_bf + bl0 * DI + d;
    const float* Bg = xdbl + bl0 * 48 + 16;  // uniform across block
    float h[16] = {};
    float ds = 0.f;
#pragma unroll 4
    for (int s = 0; s < CH; s++) {
        float de = bf2f(dl[(size_t)s * DI]);
        float uu = bf2f(ul[(size_t)s * DI]);
        float du = de * uu;
        ds += de;
        float pw[16];
        if (fast) {
            float p1 = __expf(-de);
            float p2 = p1 * p1, p4 = p2 * p2, p8 = p4 * p4;
            pw[0] = p1; pw[1] = p2; pw[2] = p2 * p1; pw[3] = p4;
            pw[4] = p4 * p1; pw[5] = p4 * p2; pw[6] = p4 * pw[2]; pw[7] = p8;
            pw[8] = p8 * p1; pw[9] = p8 * p2; pw[10] = p8 * pw[2]; pw[11] = p8 * p4;
            pw[12] = p8 * pw[4]; pw[13] = p8 * pw[5]; pw[14] = p8 * pw[6]; pw[15] = p8 * p8;
        } else {
#pragma unroll
            for (int n = 0; n < 16; n++) pw[n] = __expf(de * Av[n]);
        }
#pragma unroll
        for (int q = 0; q < 4; q++) {
            f32x4 Bv = *(const f32x4*)(Bg + (size_t)s * 48 + q * 4);
#pragma unroll
            for (int j = 0; j < 4; j++) {
                int n = q * 4 + j;
                h[n] = pw[n] * h[n] + du * Bv[j];
            }
        }
    }
    size_t base = ((size_t)b * NC + c) * DI + d;
#pragma unroll
    for (int n = 0; n < 16; n++) hend[base * 16 + n] = f2bf(h[n]);
    dsum[base] = ds;
}

// ---------------------------------------------------------------------------
// K4b: sequential chunk fix-up (bf16 hend/hinit)
// ---------------------------------------------------------------------------
__global__ __launch_bounds__(256) void k_scanB(const float* __restrict__ A_log,
                                               const float* __restrict__ dsum,
                                               const u16* __restrict__ hend,
                                               u16* __restrict__ hinit) {
    int idx = blockIdx.x * 256 + threadIdx.x;
    int n = idx & 15;
    int d = (idx >> 4) & 511;
    int b = idx >> 13;
    float Av = -__expf(A_log[d * 16 + n]);
    float h = 0.f;
#pragma unroll 8
    for (int c = 0; c < NC; c++) {
        size_t base = ((size_t)b * NC + c) * DI + d;
        hinit[base * 16 + n] = f2bf(h);
        h = __expf(dsum[base] * Av) * h + bf2f(hend[base * 16 + n]);
    }
}

// ---------------------------------------------------------------------------
// K4c: replay; y = (h.C + D*u)*silu(z). B/C via uniform global (scalar) loads.
// ---------------------------------------------------------------------------
__global__ __launch_bounds__(256) void k_scanC(const u16* __restrict__ delta_bf,
                                               const float* __restrict__ xdbl,
                                               const u16* __restrict__ u_bf,
                                               const u16* __restrict__ xz,
                                               const float* __restrict__ A_log,
                                               const float* __restrict__ Dp,
                                               const u16* __restrict__ hinit,
                                               u16* __restrict__ y_bf) {
    const int t = threadIdx.x;
    const int d = blockIdx.y * 256 + t;
    const int b = blockIdx.z;
    const int c = blockIdx.x;
    const int l0 = c * CH;
    const size_t bl0 = (size_t)b * LL + l0;
    float Av[16];
    bool fast = true;
    {
        const float4* Ar = (const float4*)(A_log + (size_t)d * 16);
#pragma unroll
        for (int q = 0; q < 4; q++) {
            float4 a = Ar[q];
            Av[q * 4] = -__expf(a.x); Av[q * 4 + 1] = -__expf(a.y);
            Av[q * 4 + 2] = -__expf(a.z); Av[q * 4 + 3] = -__expf(a.w);
        }
#pragma unroll
        for (int n = 0; n < 16; n++)
            fast = fast && (fabsf(Av[n] + (float)(n + 1)) < 1e-4f * (n + 1));
    }
    float h[16];
    {
        size_t base = ((size_t)b * NC + c) * DI + d;
#pragma unroll
        for (int n = 0; n < 16; n++) h[n] = bf2f(hinit[base * 16 + n]);
    }
    const u16* dl = delta_bf + bl0 * DI + d;
    const u16* ul = u_bf + bl0 * DI + d;
    const u16* zl = xz + bl0 * 1024 + 512 + d;
    u16* yl = y_bf + bl0 * DI + d;
    const float* Bg = xdbl + bl0 * 48 + 16;  // uniform
    const float* Cg = xdbl + bl0 * 48 + 32;  // uniform
    const float Dv = Dp[d];
#pragma unroll 4
    for (int s = 0; s < CH; s++) {
        float de = bf2f(dl[(size_t)s * DI]);
        float uu = bf2f(ul[(size_t)s * DI]);
        float zz = bf2f(zl[(size_t)s * 1024]);
        float du = de * uu;
        float pw[16];
        if (fast) {
            float p1 = __expf(-de);
            float p2 = p1 * p1, p4 = p2 * p2, p8 = p4 * p4;
            pw[0] = p1; pw[1] = p2; pw[2] = p2 * p1; pw[3] = p4;
            pw[4] = p4 * p1; pw[5] = p4 * p2; pw[6] = p4 * pw[2]; pw[7] = p8;
            pw[8] = p8 * p1; pw[9] = p8 * p2; pw[10] = p8 * pw[2]; pw[11] = p8 * p4;
            pw[12] = p8 * pw[4]; pw[13] = p8 * pw[5]; pw[14] = p8 * pw[6]; pw[15] = p8 * p8;
        } else {
#pragma unroll
            for (int n = 0; n < 16; n++) pw[n] = __expf(de * Av[n]);
        }
        float dot = 0.f;
#pragma unroll
        for (int q = 0; q < 4; q++) {
            f32x4 Bv = *(const f32x4*)(Bg + (size_t)s * 48 + q * 4);
            f32x4 Cv = *(const f32x4*)(Cg + (size_t)s * 48 + q * 4);
#pragma unroll
            for (int j = 0; j < 4; j++) {
                int n = q * 4 + j;
                h[n] = pw[n] * h[n] + du * Bv[j];
                dot += h[n] * Cv[j];
            }
        }
        float sig = 1.f / (1.f + __expf(-zz));
        yl[(size_t)s * DI] = f2bf((dot + Dv * uu) * (zz * sig));
    }
}

// ---------------------------------------------------------------------------
// K5: MFMA GEMM  out[b][o][l] = sum_d W_out[o][d]*y[b][l][d] + x[b][o][l]
// ---------------------------------------------------------------------------
__global__ __launch_bounds__(256) void k_gemm_out(const u16* __restrict__ Wb,
                                                  const u16* __restrict__ yb,
                                                  const float* __restrict__ x,
                                                  float* __restrict__ out) {
    __shared__ short As[64 * 64];
    __shared__ short Bs[128 * 64];
    const int b = blockIdx.z;
    const int l0 = blockIdx.x * 128;
    const int o0 = blockIdx.y * 64;
    const int t = threadIdx.x;
    const int lane = t & 63, wv = t >> 6;
    const u16* ybb = yb + (size_t)b * LL * DI;
    f32x4 acc[4][2] = {};
    for (int k0 = 0; k0 < DI; k0 += 64) {
#pragma unroll
        for (int i = 0; i < 2; i++) {
            int ci = t + i * 256;
            int r = ci >> 3;
            int cb = (ci & 7) * 16;
            int pd = r * 128 + (cb ^ ((r & 7) << 4));
            *(float4*)((char*)As + pd) =
                *(const float4*)((const char*)(Wb + (size_t)(o0 + r) * DI + k0) + cb);
        }
#pragma unroll
        for (int i = 0; i < 4; i++) {
            int ci = t + i * 256;
            int r = ci >> 3;
            int cb = (ci & 7) * 16;
            int pd = r * 128 + (cb ^ ((r & 7) << 4));
            *(float4*)((char*)Bs + pd) =
                *(const float4*)((const char*)(ybb + (size_t)(l0 + r) * DI + k0) + cb);
        }
        __syncthreads();
#pragma unroll
        for (int kk = 0; kk < 2; kk++) {
            const int lcb = kk * 64 + (lane >> 4) * 16;
            bf16x8 af[4], bfr[2];
#pragma unroll
            for (int mi = 0; mi < 4; mi++) {
                int r = mi * 16 + (lane & 15);
                af[mi] = *(const bf16x8*)((const char*)As + r * 128 + (lcb ^ ((r & 7) << 4)));
            }
#pragma unroll
            for (int ni = 0; ni < 2; ni++) {
                int r = wv * 32 + ni * 16 + (lane & 15);
                bfr[ni] = *(const bf16x8*)((const char*)Bs + r * 128 + (lcb ^ ((r & 7) << 4)));
            }
#pragma unroll
            for (int mi = 0; mi < 4; mi++)
#pragma unroll
                for (int ni = 0; ni < 2; ni++)
                    acc[mi][ni] = __builtin_amdgcn_mfma_f32_16x16x32_bf16(
                        af[mi], bfr[ni], acc[mi][ni], 0, 0, 0);
        }
        __syncthreads();
    }
#pragma unroll
    for (int mi = 0; mi < 4; mi++) {
#pragma unroll
        for (int q = 0; q < 4; q++) {
            int o = o0 + mi * 16 + (lane >> 4) * 4 + q;
#pragma unroll
            for (int ni = 0; ni < 2; ni++) {
                int l = l0 + wv * 32 + ni * 16 + (lane & 15);
                size_t a = ((size_t)b * DM + o) * LL + l;
                out[a] = acc[mi][ni][q] + x[a];
            }
        }
    }
}

// ---------------------------------------------------------------------------
extern "C" void kernel_launch(void* const* d_in, const int* in_sizes, int n_in,
                              void* d_out, int out_size, void* d_ws, size_t ws_size,
                              hipStream_t stream) {
    const float* x = (const float*)d_in[0];
    const float* W_in = (const float*)d_in[1];
    const float* W_dw = (const float*)d_in[2];
    const float* b_dw = (const float*)d_in[3];
    const float* W_x = (const float*)d_in[4];
    const float* W_dt = (const float*)d_in[5];
    const float* b_dt = (const float*)d_in[6];
    const float* A_log = (const float*)d_in[7];
    const float* Dp = (const float*)d_in[8];
    const float* W_out = (const float*)d_in[9];
    float* out = (float*)d_out;

    char* p = (char*)d_ws;
    u16* xz_bf = (u16*)p;      p += (size_t)BB * LL * 1024 * 2;    // 16.8 MB
    u16* u_bf = (u16*)p;       p += (size_t)BB * LL * DI * 2;      // 8.4 MB
    u16* delta_bf = (u16*)p;   p += (size_t)BB * LL * DI * 2;      // 8.4 MB
    float* xdbl = (float*)p;   p += (size_t)BB * LL * 48 * 4;      // 1.6 MB
    float* xdbl_p = (float*)p; p += (size_t)4 * BB * LL * 48 * 4;  // 6.3 MB
    u16* y_bf = (u16*)p;       p += (size_t)BB * LL * DI * 2;      // 8.4 MB
    float* dsum = (float*)p;   p += (size_t)BB * NC * DI * 4;      // 0.5 MB
    u16* hinit = (u16*)p;      p += (size_t)BB * NC * DI * 16 * 2; // 4.2 MB
    u16* wbf_in = (u16*)p;     p += (size_t)2 * DI * DM * 2;
    u16* wbf_out = (u16*)p;    p += (size_t)DM * DI * 2;
    u16* wbf_x = (u16*)p;      p += (size_t)48 * DI * 2;
    // aliases (lifetime-disjoint):
    u16* xt = delta_bf;  // xt dead (after gemm_in) before k_delta writes delta
    u16* hend = y_bf;    // hend dead (after scanB) before scanC writes y

    k_prep<<<920, 256, 0, stream>>>(x, W_in, W_out, W_x, xt, wbf_in, wbf_out, wbf_x);
    k_gemm_in<<<dim3(LL / 128, 1024 / 128, BB), 256, 0, stream>>>(xt, wbf_in, xz_bf);
    k_conv<<<(BB * LL * 64) / 256, 256, 0, stream>>>(xz_bf, W_dw, b_dw, u_bf);
    k_xdbl<<<(BB * LL / 64) * 4, 256, 0, stream>>>(u_bf, wbf_x, xdbl_p);
    k_delta<<<BB * LL / 16, 256, 0, stream>>>(xdbl_p, W_dt, b_dt, xdbl, delta_bf);
    k_scanA<<<dim3(NC, DI / 256, BB), 256, 0, stream>>>(delta_bf, xdbl, u_bf, A_log,
                                                        hend, dsum);
    k_scanB<<<(BB * DI * 16) / 256, 256, 0, stream>>>(A_log, dsum, hend, hinit);
    k_scanC<<<dim3(NC, DI / 256, BB), 256, 0, stream>>>(delta_bf, xdbl, u_bf, xz_bf,
                                                        A_log, Dp, hinit, y_bf);
    k_gemm_out<<<dim3(LL / 128, DM / 64, BB), 256, 0, stream>>>(wbf_out, y_bf, x, out);
}

// Round 9
// 87.023 us; speedup vs baseline: 1.0746x; 1.0746x over previous
//
#include <hip/hip_runtime.h>
#include <math.h>

#define DM 256
#define DI 512
#define BB 4
#define LL 2048
#define NC 128
#define CH (LL / NC)  // 16

typedef short bf16x8 __attribute__((ext_vector_type(8)));
typedef float f32x4 __attribute__((ext_vector_type(4)));
typedef unsigned short u16;

__device__ inline u16 f2bf(float f) {
    union { float f; unsigned u; } v;
    v.f = f;
    return (u16)((v.u + 0x7FFF + ((v.u >> 16) & 1)) >> 16);
}
__device__ inline float bf2f(u16 h) {
    union { unsigned u; float f; } v;
    v.u = ((unsigned)h) << 16;
    return v.f;
}

// Async global->LDS, 16B per lane. LDS dest is wave-uniform base + lane*16
// (linear); the global source carries the XOR swizzle (rule #21: swizzle
// source + read, keep LDS write linear).
__device__ inline void gload_lds16(const void* g, void* l) {
    auto* gp = reinterpret_cast<const __attribute__((address_space(1))) unsigned int*>(
        reinterpret_cast<uintptr_t>(g));
    auto* lp = reinterpret_cast<__attribute__((address_space(3))) unsigned int*>(
        reinterpret_cast<uintptr_t>(l));
    __builtin_amdgcn_global_load_lds(gp, lp, 16, 0, 0);
}

// ---------------------------------------------------------------------------
// K0: ALL prep in one launch.
// bid [0,512):   x[b][m][l] fp32 -> xt[b][l][m] bf16 (64x64 transpose tiles)
// bid [512,768): W_in cvt   bid [768,896): W_out cvt   bid [896,920): W_x cvt
// ---------------------------------------------------------------------------
__global__ __launch_bounds__(256) void k_prep(const float* __restrict__ x,
                                              const float* __restrict__ W_in,
                                              const float* __restrict__ W_out,
                                              const float* __restrict__ W_x,
                                              u16* __restrict__ xt,
                                              u16* __restrict__ wbf_in,
                                              u16* __restrict__ wbf_out,
                                              u16* __restrict__ wbf_x) {
    const int bid = blockIdx.x;
    const int t = threadIdx.x;
    if (bid < 512) {
        __shared__ float tile[64][65];
        const int lb = bid & 31, mb = (bid >> 5) & 3, b = bid >> 7;
        const int m0 = mb * 64, l0 = lb * 64;
        const float* xb = x + ((size_t)b * DM + m0) * LL + l0;
#pragma unroll
        for (int i = 0; i < 16; i++) {
            int idx = t + i * 256;
            int r = idx >> 6, c = idx & 63;
            tile[r][c] = xb[(size_t)r * LL + c];
        }
        __syncthreads();
        u16* ob = xt + ((size_t)b * LL + l0) * DM + m0;
#pragma unroll
        for (int i = 0; i < 16; i++) {
            int idx = t + i * 256;
            int r = idx >> 6, c = idx & 63;
            ob[(size_t)r * DM + c] = f2bf(tile[c][r]);
        }
        return;
    }
    const float* src;
    u16* dst;
    int i4;
    if (bid < 768) { src = W_in; dst = wbf_in; i4 = (bid - 512) * 256 + t; }
    else if (bid < 896) { src = W_out; dst = wbf_out; i4 = (bid - 768) * 256 + t; }
    else { src = W_x; dst = wbf_x; i4 = (bid - 896) * 256 + t; }
    float4 v = ((const float4*)src)[i4];
    unsigned o0 = (unsigned)f2bf(v.x) | ((unsigned)f2bf(v.y) << 16);
    unsigned o1 = (unsigned)f2bf(v.z) | ((unsigned)f2bf(v.w) << 16);
    ((uint2*)dst)[i4] = make_uint2(o0, o1);
}

// ---------------------------------------------------------------------------
// K1: MFMA GEMM  xz[b][l][c] (bf16) = sum_m xt[b][l][m] * W_in[c][m]
// 128x128 tile, BK=64, 4 waves 2x2, global_load_lds staging (pre-swz source).
// ---------------------------------------------------------------------------
__global__ __launch_bounds__(256) void k_gemm_in(const u16* __restrict__ xt,
                                                 const u16* __restrict__ Wb,
                                                 u16* __restrict__ xz) {
    __shared__ short As[128 * 64];
    __shared__ short Bs[128 * 64];
    const int b = blockIdx.z;
    const int l0 = blockIdx.x * 128;
    const int c0 = blockIdx.y * 128;
    const int t = threadIdx.x;
    const int lane = t & 63, wv = t >> 6;
    const int wr = wv >> 1, wc = wv & 1;
    const int rsub = lane >> 3;
    const int colb = ((lane & 7) * 16) ^ ((rsub & 7) << 4);  // pre-swz src col
    const u16* xb = xt + (size_t)b * LL * DM;
    f32x4 acc[4][4] = {};
    for (int k0 = 0; k0 < DM; k0 += 64) {
#pragma unroll
        for (int i = 0; i < 4; i++) {
            int rb = wv * 32 + i * 8;  // rb%8==0 so row&7 == rsub
            int r = rb + rsub;
            gload_lds16((const char*)(xb + (size_t)(l0 + r) * DM + k0) + colb,
                        (char*)As + rb * 128);
            gload_lds16((const char*)(Wb + (size_t)(c0 + r) * DM + k0) + colb,
                        (char*)Bs + rb * 128);
        }
        __syncthreads();
#pragma unroll
        for (int kk = 0; kk < 2; kk++) {
            const int lcb = kk * 64 + (lane >> 4) * 16;
            bf16x8 af[4], bfr[4];
#pragma unroll
            for (int mi = 0; mi < 4; mi++) {
                int r = wr * 64 + mi * 16 + (lane & 15);
                af[mi] = *(const bf16x8*)((const char*)As + r * 128 + (lcb ^ ((r & 7) << 4)));
            }
#pragma unroll
            for (int ni = 0; ni < 4; ni++) {
                int r = wc * 64 + ni * 16 + (lane & 15);
                bfr[ni] = *(const bf16x8*)((const char*)Bs + r * 128 + (lcb ^ ((r & 7) << 4)));
            }
#pragma unroll
            for (int mi = 0; mi < 4; mi++)
#pragma unroll
                for (int ni = 0; ni < 4; ni++)
                    acc[mi][ni] = __builtin_amdgcn_mfma_f32_16x16x32_bf16(
                        af[mi], bfr[ni], acc[mi][ni], 0, 0, 0);
        }
        __syncthreads();
    }
    u16* ob = xz + (size_t)b * LL * 1024;
#pragma unroll
    for (int mi = 0; mi < 4; mi++) {
#pragma unroll
        for (int q = 0; q < 4; q++) {
            int l = l0 + wr * 64 + mi * 16 + (lane >> 4) * 4 + q;
#pragma unroll
            for (int ni = 0; ni < 4; ni++) {
                int c = c0 + wc * 64 + ni * 16 + (lane & 15);
                ob[(size_t)l * 1024 + c] = f2bf(acc[mi][ni][q]);
            }
        }
    }
}

// ---------------------------------------------------------------------------
// K2a: depthwise conv k=3 + bias + silu, bf16->bf16, 8 d's/thread, 2048 blocks
// ---------------------------------------------------------------------------
__global__ __launch_bounds__(256) void k_conv(const u16* __restrict__ xz,
                                              const float* __restrict__ Wdw,
                                              const float* __restrict__ bdw,
                                              u16* __restrict__ u_bf) {
    int idx = blockIdx.x * 256 + threadIdx.x;  // over BB*LL*64 groups of 8
    int g = idx & 63;
    int l = (idx >> 6) & (LL - 1);
    int b = idx >> 17;
    int d0 = g * 8;
    const u16* row = xz + ((size_t)b * LL + l) * 1024 + d0;
    ushort4 c0a = *(const ushort4*)(row);
    ushort4 c0b = *(const ushort4*)(row + 4);
    ushort4 cma, cmb, cpa, cpb;
    if (l > 0) { cma = *(const ushort4*)(row - 1024); cmb = *(const ushort4*)(row - 1020); }
    else { cma = make_ushort4(0, 0, 0, 0); cmb = cma; }
    if (l < LL - 1) { cpa = *(const ushort4*)(row + 1024); cpb = *(const ushort4*)(row + 1028); }
    else { cpa = make_ushort4(0, 0, 0, 0); cpb = cpa; }
    u16 xm[8] = {cma.x, cma.y, cma.z, cma.w, cmb.x, cmb.y, cmb.z, cmb.w};
    u16 x0[8] = {c0a.x, c0a.y, c0a.z, c0a.w, c0b.x, c0b.y, c0b.z, c0b.w};
    u16 xp[8] = {cpa.x, cpa.y, cpa.z, cpa.w, cpb.x, cpb.y, cpb.z, cpb.w};
    u16 out[8];
#pragma unroll
    for (int j = 0; j < 8; j++) {
        int d = d0 + j;
        float v = bdw[d] + Wdw[d * 3] * bf2f(xm[j]) + Wdw[d * 3 + 1] * bf2f(x0[j]) +
                  Wdw[d * 3 + 2] * bf2f(xp[j]);
        float uu = v / (1.f + __expf(-v));
        out[j] = f2bf(uu);
    }
    u16* ou = u_bf + ((size_t)b * LL + l) * DI + d0;
    *(ushort4*)(ou) = make_ushort4(out[0], out[1], out[2], out[3]);
    *(ushort4*)(ou + 4) = make_ushort4(out[4], out[5], out[6], out[7]);
}

// ---------------------------------------------------------------------------
// K2b: split-K MFMA GEMM  xdbl_p[kp][bl][c] = sum_{d in kp-chunk} u*Wx
// grid = 512 blocks: (bl-tile of 64 rows) x (kp in 0..3, K=128 each)
// ---------------------------------------------------------------------------
__global__ __launch_bounds__(256) void k_xdbl(const u16* __restrict__ u_bf,
                                              const u16* __restrict__ Wxb,
                                              float* __restrict__ xdbl_p) {
    __shared__ short Us[64 * 64];
    __shared__ short Ws[48 * 64];
    const int bl0 = (blockIdx.x >> 2) * 64;
    const int kp = blockIdx.x & 3;
    const int t = threadIdx.x;
    const int lane = t & 63, wv = t >> 6;
    const int rsub = lane >> 3;
    const int colb = ((lane & 7) * 16) ^ ((rsub & 7) << 4);
    f32x4 acc[3] = {};
#pragma unroll
    for (int ks = 0; ks < 2; ks++) {
        const int k0 = kp * 128 + ks * 64;
        if (ks) __syncthreads();
#pragma unroll
        for (int i = 0; i < 2; i++) {
            int rb = wv * 16 + i * 8;
            int r = rb + rsub;
            gload_lds16((const char*)(u_bf + (size_t)(bl0 + r) * DI + k0) + colb,
                        (char*)Us + rb * 128);
            if (wv < 3)
                gload_lds16((const char*)(Wxb + (size_t)r * DI + k0) + colb,
                            (char*)Ws + rb * 128);
        }
        __syncthreads();
#pragma unroll
        for (int kk = 0; kk < 2; kk++) {
            int lcb = kk * 64 + (lane >> 4) * 16;
            int ra = wv * 16 + (lane & 15);
            bf16x8 af = *(const bf16x8*)((const char*)Us + ra * 128 + (lcb ^ ((ra & 7) << 4)));
#pragma unroll
            for (int ni = 0; ni < 3; ni++) {
                int r2 = ni * 16 + (lane & 15);
                bf16x8 bfr = *(const bf16x8*)((const char*)Ws + r2 * 128 + (lcb ^ ((r2 & 7) << 4)));
                acc[ni] = __builtin_amdgcn_mfma_f32_16x16x32_bf16(af, bfr, acc[ni], 0, 0, 0);
            }
        }
    }
#pragma unroll
    for (int ni = 0; ni < 3; ni++)
#pragma unroll
        for (int q = 0; q < 4; q++) {
            int l = bl0 + wv * 16 + (lane >> 4) * 4 + q;
            int c = ni * 16 + (lane & 15);
            xdbl_p[((size_t)kp * BB * LL + l) * 48 + c] = acc[ni][q];
        }
}

// ---------------------------------------------------------------------------
// K3: reduce split-K partials -> xdbl (final) ; delta = softplus(...) -> bf16
// ---------------------------------------------------------------------------
__global__ __launch_bounds__(256) void k_delta(const float* __restrict__ xdbl_p,
                                               const float* __restrict__ Wdt,
                                               const float* __restrict__ bdt,
                                               float* __restrict__ xdbl,
                                               u16* __restrict__ delta_bf) {
    __shared__ float xd[16][52];
    const int bl0 = blockIdx.x * 16;
    const int t = threadIdx.x;
#pragma unroll
    for (int i = 0; i < 3; i++) {
        int idx = t + i * 256;  // 0..767 = 16 rows x 48 cols
        int l = idx / 48, c = idx - l * 48;
        size_t off = (size_t)(bl0 + l) * 48 + c;
        float s = xdbl_p[off] + xdbl_p[(size_t)BB * LL * 48 + off] +
                  xdbl_p[(size_t)2 * BB * LL * 48 + off] +
                  xdbl_p[(size_t)3 * BB * LL * 48 + off];
        xd[l][c] = s;
        xdbl[off] = s;
    }
    __syncthreads();
    float wr0[16], wr1[16];
    {
        const float4* wp0 = (const float4*)(Wdt + (size_t)t * 16);
        const float4* wp1 = (const float4*)(Wdt + (size_t)(t + 256) * 16);
#pragma unroll
        for (int q = 0; q < 4; q++) {
            float4 w = wp0[q];
            wr0[q * 4] = w.x; wr0[q * 4 + 1] = w.y; wr0[q * 4 + 2] = w.z; wr0[q * 4 + 3] = w.w;
            float4 u = wp1[q];
            wr1[q * 4] = u.x; wr1[q * 4 + 1] = u.y; wr1[q * 4 + 2] = u.z; wr1[q * 4 + 3] = u.w;
        }
    }
    const float b0 = bdt[t], b1 = bdt[t + 256];
#pragma unroll 4
    for (int ll = 0; ll < 16; ll++) {
        float a0 = b0, a1 = b1;
#pragma unroll
        for (int q = 0; q < 4; q++) {
            f32x4 xv = *(const f32x4*)&xd[ll][q * 4];
#pragma unroll
            for (int j = 0; j < 4; j++) {
                a0 += wr0[q * 4 + j] * xv[j];
                a1 += wr1[q * 4 + j] * xv[j];
            }
        }
        float sp0 = fmaxf(a0, 0.f) + __logf(1.f + __expf(-fabsf(a0)));
        float sp1 = fmaxf(a1, 0.f) + __logf(1.f + __expf(-fabsf(a1)));
        delta_bf[(size_t)(bl0 + ll) * DI + t] = f2bf(sp0);
        delta_bf[(size_t)(bl0 + ll) * DI + t + 256] = f2bf(sp1);
    }
}

// ---------------------------------------------------------------------------
// K4a: per-chunk local scan (CH=16, 1024 blocks = 4/CU for latency hiding)
// ---------------------------------------------------------------------------
__global__ __launch_bounds__(256) void k_scanA(const u16* __restrict__ delta_bf,
                                               const float* __restrict__ xdbl,
                                               const u16* __restrict__ u_bf,
                                               const float* __restrict__ A_log,
                                               u16* __restrict__ hend,
                                               float* __restrict__ dsum) {
    const int t = threadIdx.x;
    const int d = blockIdx.y * 256 + t;
    const int b = blockIdx.z;
    const int c = blockIdx.x;
    const int l0 = c * CH;
    const size_t bl0 = (size_t)b * LL + l0;
    float Av[16];
    bool fast = true;
    {
        const float4* Ar = (const float4*)(A_log + (size_t)d * 16);
#pragma unroll
        for (int q = 0; q < 4; q++) {
            float4 a = Ar[q];
            Av[q * 4] = -__expf(a.x); Av[q * 4 + 1] = -__expf(a.y);
            Av[q * 4 + 2] = -__expf(a.z); Av[q * 4 + 3] = -__expf(a.w);
        }
#pragma unroll
        for (int n = 0; n < 16; n++)
            fast = fast && (fabsf(Av[n] + (float)(n + 1)) < 1e-4f * (n + 1));
    }
    const u16* dl = delta_bf + bl0 * DI + d;
    const u16* ul = u_bf + bl0 * DI + d;
    const float* Bg = xdbl + bl0 * 48 + 16;
    float h[16] = {};
    float ds = 0.f;
#pragma unroll 4
    for (int s = 0; s < CH; s++) {
        float de = bf2f(dl[(size_t)s * DI]);
        float uu = bf2f(ul[(size_t)s * DI]);
        float du = de * uu;
        ds += de;
        float pw[16];
        if (fast) {
            float p1 = __expf(-de);
            float p2 = p1 * p1, p4 = p2 * p2, p8 = p4 * p4;
            pw[0] = p1; pw[1] = p2; pw[2] = p2 * p1; pw[3] = p4;
            pw[4] = p4 * p1; pw[5] = p4 * p2; pw[6] = p4 * pw[2]; pw[7] = p8;
            pw[8] = p8 * p1; pw[9] = p8 * p2; pw[10] = p8 * pw[2]; pw[11] = p8 * p4;
            pw[12] = p8 * pw[4]; pw[13] = p8 * pw[5]; pw[14] = p8 * pw[6]; pw[15] = p8 * p8;
        } else {
#pragma unroll
            for (int n = 0; n < 16; n++) pw[n] = __expf(de * Av[n]);
        }
#pragma unroll
        for (int q = 0; q < 4; q++) {
            f32x4 Bv = *(const f32x4*)(Bg + (size_t)s * 48 + q * 4);
#pragma unroll
            for (int j = 0; j < 4; j++) {
                int n = q * 4 + j;
                h[n] = pw[n] * h[n] + du * Bv[j];
            }
        }
    }
    size_t base = ((size_t)b * NC + c) * DI + d;
#pragma unroll
    for (int n = 0; n < 16; n++) hend[base * 16 + n] = f2bf(h[n]);
    dsum[base] = ds;
}

// ---------------------------------------------------------------------------
// K4b: sequential chunk fix-up (bf16 hend/hinit), NC=128 serial links
// ---------------------------------------------------------------------------
__global__ __launch_bounds__(256) void k_scanB(const float* __restrict__ A_log,
                                               const float* __restrict__ dsum,
                                               const u16* __restrict__ hend,
                                               u16* __restrict__ hinit) {
    int idx = blockIdx.x * 256 + threadIdx.x;
    int n = idx & 15;
    int d = (idx >> 4) & 511;
    int b = idx >> 13;
    float Av = -__expf(A_log[d * 16 + n]);
    float h = 0.f;
#pragma unroll 8
    for (int c = 0; c < NC; c++) {
        size_t base = ((size_t)b * NC + c) * DI + d;
        hinit[base * 16 + n] = f2bf(h);
        h = __expf(dsum[base] * Av) * h + bf2f(hend[base * 16 + n]);
    }
}

// ---------------------------------------------------------------------------
// K4c: replay; y = (h.C + D*u)*silu(z)
// ---------------------------------------------------------------------------
__global__ __launch_bounds__(256) void k_scanC(const u16* __restrict__ delta_bf,
                                               const float* __restrict__ xdbl,
                                               const u16* __restrict__ u_bf,
                                               const u16* __restrict__ xz,
                                               const float* __restrict__ A_log,
                                               const float* __restrict__ Dp,
                                               const u16* __restrict__ hinit,
                                               u16* __restrict__ y_bf) {
    const int t = threadIdx.x;
    const int d = blockIdx.y * 256 + t;
    const int b = blockIdx.z;
    const int c = blockIdx.x;
    const int l0 = c * CH;
    const size_t bl0 = (size_t)b * LL + l0;
    float Av[16];
    bool fast = true;
    {
        const float4* Ar = (const float4*)(A_log + (size_t)d * 16);
#pragma unroll
        for (int q = 0; q < 4; q++) {
            float4 a = Ar[q];
            Av[q * 4] = -__expf(a.x); Av[q * 4 + 1] = -__expf(a.y);
            Av[q * 4 + 2] = -__expf(a.z); Av[q * 4 + 3] = -__expf(a.w);
        }
#pragma unroll
        for (int n = 0; n < 16; n++)
            fast = fast && (fabsf(Av[n] + (float)(n + 1)) < 1e-4f * (n + 1));
    }
    float h[16];
    {
        size_t base = ((size_t)b * NC + c) * DI + d;
#pragma unroll
        for (int n = 0; n < 16; n++) h[n] = bf2f(hinit[base * 16 + n]);
    }
    const u16* dl = delta_bf + bl0 * DI + d;
    const u16* ul = u_bf + bl0 * DI + d;
    const u16* zl = xz + bl0 * 1024 + 512 + d;
    u16* yl = y_bf + bl0 * DI + d;
    const float* Bg = xdbl + bl0 * 48 + 16;
    const float* Cg = xdbl + bl0 * 48 + 32;
    const float Dv = Dp[d];
#pragma unroll 4
    for (int s = 0; s < CH; s++) {
        float de = bf2f(dl[(size_t)s * DI]);
        float uu = bf2f(ul[(size_t)s * DI]);
        float zz = bf2f(zl[(size_t)s * 1024]);
        float du = de * uu;
        float pw[16];
        if (fast) {
            float p1 = __expf(-de);
            float p2 = p1 * p1, p4 = p2 * p2, p8 = p4 * p4;
            pw[0] = p1; pw[1] = p2; pw[2] = p2 * p1; pw[3] = p4;
            pw[4] = p4 * p1; pw[5] = p4 * p2; pw[6] = p4 * pw[2]; pw[7] = p8;
            pw[8] = p8 * p1; pw[9] = p8 * p2; pw[10] = p8 * pw[2]; pw[11] = p8 * p4;
            pw[12] = p8 * pw[4]; pw[13] = p8 * pw[5]; pw[14] = p8 * pw[6]; pw[15] = p8 * p8;
        } else {
#pragma unroll
            for (int n = 0; n < 16; n++) pw[n] = __expf(de * Av[n]);
        }
        float dot = 0.f;
#pragma unroll
        for (int q = 0; q < 4; q++) {
            f32x4 Bv = *(const f32x4*)(Bg + (size_t)s * 48 + q * 4);
            f32x4 Cv = *(const f32x4*)(Cg + (size_t)s * 48 + q * 4);
#pragma unroll
            for (int j = 0; j < 4; j++) {
                int n = q * 4 + j;
                h[n] = pw[n] * h[n] + du * Bv[j];
                dot += h[n] * Cv[j];
            }
        }
        float sig = 1.f / (1.f + __expf(-zz));
        yl[(size_t)s * DI] = f2bf((dot + Dv * uu) * (zz * sig));
    }
}

// ---------------------------------------------------------------------------
// K5: MFMA GEMM  out[b][o][l] = sum_d W_out[o][d]*y[b][l][d] + x[b][o][l]
// ---------------------------------------------------------------------------
__global__ __launch_bounds__(256) void k_gemm_out(const u16* __restrict__ Wb,
                                                  const u16* __restrict__ yb,
                                                  const float* __restrict__ x,
                                                  float* __restrict__ out) {
    __shared__ short As[64 * 64];
    __shared__ short Bs[128 * 64];
    const int b = blockIdx.z;
    const int l0 = blockIdx.x * 128;
    const int o0 = blockIdx.y * 64;
    const int t = threadIdx.x;
    const int lane = t & 63, wv = t >> 6;
    const int rsub = lane >> 3;
    const int colb = ((lane & 7) * 16) ^ ((rsub & 7) << 4);
    const u16* ybb = yb + (size_t)b * LL * DI;
    f32x4 acc[4][2] = {};
    for (int k0 = 0; k0 < DI; k0 += 64) {
#pragma unroll
        for (int i = 0; i < 2; i++) {
            int rb = wv * 16 + i * 8;
            int r = rb + rsub;
            gload_lds16((const char*)(Wb + (size_t)(o0 + r) * DI + k0) + colb,
                        (char*)As + rb * 128);
        }
#pragma unroll
        for (int i = 0; i < 4; i++) {
            int rb = wv * 32 + i * 8;
            int r = rb + rsub;
            gload_lds16((const char*)(ybb + (size_t)(l0 + r) * DI + k0) + colb,
                        (char*)Bs + rb * 128);
        }
        __syncthreads();
#pragma unroll
        for (int kk = 0; kk < 2; kk++) {
            const int lcb = kk * 64 + (lane >> 4) * 16;
            bf16x8 af[4], bfr[2];
#pragma unroll
            for (int mi = 0; mi < 4; mi++) {
                int r = mi * 16 + (lane & 15);
                af[mi] = *(const bf16x8*)((const char*)As + r * 128 + (lcb ^ ((r & 7) << 4)));
            }
#pragma unroll
            for (int ni = 0; ni < 2; ni++) {
                int r = wv * 32 + ni * 16 + (lane & 15);
                bfr[ni] = *(const bf16x8*)((const char*)Bs + r * 128 + (lcb ^ ((r & 7) << 4)));
            }
#pragma unroll
            for (int mi = 0; mi < 4; mi++)
#pragma unroll
                for (int ni = 0; ni < 2; ni++)
                    acc[mi][ni] = __builtin_amdgcn_mfma_f32_16x16x32_bf16(
                        af[mi], bfr[ni], acc[mi][ni], 0, 0, 0);
        }
        __syncthreads();
    }
#pragma unroll
    for (int mi = 0; mi < 4; mi++) {
#pragma unroll
        for (int q = 0; q < 4; q++) {
            int o = o0 + mi * 16 + (lane >> 4) * 4 + q;
#pragma unroll
            for (int ni = 0; ni < 2; ni++) {
                int l = l0 + wv * 32 + ni * 16 + (lane & 15);
                size_t a = ((size_t)b * DM + o) * LL + l;
                out[a] = acc[mi][ni][q] + x[a];
            }
        }
    }
}

// ---------------------------------------------------------------------------
extern "C" void kernel_launch(void* const* d_in, const int* in_sizes, int n_in,
                              void* d_out, int out_size, void* d_ws, size_t ws_size,
                              hipStream_t stream) {
    const float* x = (const float*)d_in[0];
    const float* W_in = (const float*)d_in[1];
    const float* W_dw = (const float*)d_in[2];
    const float* b_dw = (const float*)d_in[3];
    const float* W_x = (const float*)d_in[4];
    const float* W_dt = (const float*)d_in[5];
    const float* b_dt = (const float*)d_in[6];
    const float* A_log = (const float*)d_in[7];
    const float* Dp = (const float*)d_in[8];
    const float* W_out = (const float*)d_in[9];
    float* out = (float*)d_out;

    char* p = (char*)d_ws;
    u16* xz_bf = (u16*)p;      p += (size_t)BB * LL * 1024 * 2;    // 16.8 MB
    u16* u_bf = (u16*)p;       p += (size_t)BB * LL * DI * 2;      // 8.4 MB
    u16* delta_bf = (u16*)p;   p += (size_t)BB * LL * DI * 2;      // 8.4 MB
    float* xdbl = (float*)p;   p += (size_t)BB * LL * 48 * 4;      // 1.6 MB
    float* xdbl_p = (float*)p; p += (size_t)4 * BB * LL * 48 * 4;  // 6.3 MB
    u16* y_bf = (u16*)p;       p += (size_t)BB * LL * DI * 2;      // 8.4 MB
    float* dsum = (float*)p;   p += (size_t)BB * NC * DI * 4;      // 1.0 MB
    u16* hinit = (u16*)p;      p += (size_t)BB * NC * DI * 16 * 2; // 8.4 MB
    u16* wbf_in = (u16*)p;     p += (size_t)2 * DI * DM * 2;
    u16* wbf_out = (u16*)p;    p += (size_t)DM * DI * 2;
    u16* wbf_x = (u16*)p;      p += (size_t)48 * DI * 2;
    // aliases (lifetime-disjoint):
    u16* xt = delta_bf;  // xt dead (after gemm_in) before k_delta writes delta
    u16* hend = y_bf;    // hend (8.4 MB) dead after scanB, before scanC writes y

    k_prep<<<920, 256, 0, stream>>>(x, W_in, W_out, W_x, xt, wbf_in, wbf_out, wbf_x);
    k_gemm_in<<<dim3(LL / 128, 1024 / 128, BB), 256, 0, stream>>>(xt, wbf_in, xz_bf);
    k_conv<<<(BB * LL * 64) / 256, 256, 0, stream>>>(xz_bf, W_dw, b_dw, u_bf);
    k_xdbl<<<(BB * LL / 64) * 4, 256, 0, stream>>>(u_bf, wbf_x, xdbl_p);
    k_delta<<<BB * LL / 16, 256, 0, stream>>>(xdbl_p, W_dt, b_dt, xdbl, delta_bf);
    k_scanA<<<dim3(NC, DI / 256, BB), 256, 0, stream>>>(delta_bf, xdbl, u_bf, A_log,
                                                        hend, dsum);
    k_scanB<<<(BB * DI * 16) / 256, 256, 0, stream>>>(A_log, dsum, hend, hinit);
    k_scanC<<<dim3(NC, DI / 256, BB), 256, 0, stream>>>(delta_bf, xdbl, u_bf, xz_bf,
                                                        A_log, Dp, hinit, y_bf);
    k_gemm_out<<<dim3(LL / 128, DM / 64, BB), 256, 0, stream>>>(wbf_out, y_bf, x, out);
}